// Round 21
// baseline (447.356 us; speedup 1.0000x reference)
//
#include <hip/hip_runtime.h>
#include <hip/hip_bf16.h>

#define HWF 128
#define NB  64
#define PW  30
#define PP  900

using bf16 = __hip_bfloat16;
typedef __attribute__((ext_vector_type(8)))  short short8;
typedef __attribute__((ext_vector_type(4)))  float f32x4;
typedef __attribute__((ext_vector_type(16))) float f32x16;
typedef __attribute__((ext_vector_type(4)))  unsigned int u32x4;
typedef __attribute__((ext_vector_type(2)))  unsigned int u32x2;

__device__ __forceinline__ float b2f(bf16 v) { return __bfloat162float(v); }
__device__ __forceinline__ bf16  f2b(float v){ return __float2bfloat16(v); }
__device__ __forceinline__ float u2f(unsigned short u){ unsigned x = (unsigned)u << 16; float f; __builtin_memcpy(&f,&x,4); return f; }
__device__ __forceinline__ unsigned pack2(float a, float b) {
  union { bf16 h; unsigned short u; } ca, cb; ca.h = f2b(a); cb.h = f2b(b);
  return ((unsigned)cb.u << 16) | (unsigned)ca.u;
}

// ---------------------------------------------------------------------------
// Fused prep: blocks 0..11 = head fold (weff); blocks 12..1035 = weight
// transforms w[co][ci][3][3] fp32 -> Wt[tap][cib][kh][co][koct][8e] bf16.
// ---------------------------------------------------------------------------
__global__ __launch_bounds__(256) void prep_kernel(
    const float* __restrict__ hm_dw, const float* __restrict__ hm_db,
    const float* __restrict__ hm_w,  const float* __restrict__ hm_b,
    const float* __restrict__ wh_dw, const float* __restrict__ wh_db,
    const float* __restrict__ wh_w,  const float* __restrict__ wh_b,
    float* __restrict__ Weff, float* __restrict__ beff,
    const float* __restrict__ w1, bf16* __restrict__ Wt1,
    const float* __restrict__ w2, bf16* __restrict__ Wt2,
    const float* __restrict__ w3, bf16* __restrict__ Wt3,
    const float* __restrict__ w4, bf16* __restrict__ Wt4) {
  const int b = blockIdx.x;
  if (b < 12) {
    const int k = b / 3, o = b % 3;
    const int ci = threadIdx.x;
    const float* dw = (o == 0) ? hm_dw : wh_dw;
    const float* hw = (o == 0) ? hm_w  : (wh_w + (size_t)(o - 1) * 256);
    const float* dwp = dw + (size_t)ci * 4 + k;
    float s = 0.f;
    for (int co = 0; co < 256; ++co) s += hw[co] * dwp[(size_t)co * 1024];
    Weff[(size_t)b * 256 + ci] = s;
    if (k == 0 && ci == 0) {
      const float* db = (o == 0) ? hm_db : wh_db;
      float bb = (o == 0) ? hm_b[0] : wh_b[o - 1];
      float t = 0.f;
      for (int co = 0; co < 256; ++co) t += hw[co] * db[co];
      beff[o] = bb + t;
    }
    return;
  }
  const int i = b - 12;
  const int layer = i >> 8, co = i & 255;
  const float* w; bf16* Wt; int CIN;
  if      (layer == 0) { w = w1; Wt = Wt1; CIN = 64;  }
  else if (layer == 1) { w = w2; Wt = Wt2; CIN = 256; }
  else if (layer == 2) { w = w3; Wt = Wt3; CIN = 256; }
  else                 { w = w4; Wt = Wt4; CIN = 256; }
  const int ci = threadIdx.x;
  if (ci < CIN) {
    const int NCIB = CIN >> 5;
    const int cib = ci >> 5, cl = ci & 31;
    const int kh = cl >> 4, koct = (cl >> 3) & 1, e = ci & 7;
    for (int tap = 0; tap < 9; ++tap)
      Wt[(((((size_t)tap * NCIB + cib) * 2 + kh) * 256 + co) * 2 + koct) * 8 + e]
          = f2b(w[((size_t)co * CIN + ci) * 9 + tap]);
  }
}

// ---------------------------------------------------------------------------
// Feature transpose (unchanged, verified)
// ---------------------------------------------------------------------------
__global__ __launch_bounds__(256) void featT_kernel(const float* __restrict__ feat,
                                                    bf16* __restrict__ featT) {
  const int by = blockIdx.x;
  const int b = by >> 7, y = by & 127;
  const int t = threadIdx.x;
  __shared__ float tile[128][65];
  const int xr = t & 127, c2 = t >> 7;
  for (int c0 = 0; c0 < 64; c0 += 2)
    tile[xr][c0 + c2] = feat[(((size_t)(b * 64 + c0 + c2) * 128 + y) * 128) + xr];
  __syncthreads();
  const int cw = t & 63, x4 = t >> 6;
  for (int x0 = 0; x0 < 128; x0 += 4)
    featT[(((size_t)by * 128) + x0 + x4) * 64 + cw] = f2b(tile[x0 + x4][cw]);
}

// ---------------------------------------------------------------------------
// ROI align -> roiP cob-blocked: [roi][cb 0..1][900][32ci] bf16, borders zeroed
// ---------------------------------------------------------------------------
__global__ __launch_bounds__(256) void roi_cl(const bf16* __restrict__ featT,
                                              const int* __restrict__ act_ind,
                                              const float* __restrict__ awh,
                                              bf16* __restrict__ roiP) {
  const int r = blockIdx.x, part = blockIdx.y;
  const int t = threadIdx.x;
  if (part == 7) {
    for (int i = t; i < 116 * 64; i += 256) {
      int j = i >> 6, c = i & 63;
      int py, px;
      if (j < 30)      { py = 0;      px = j;      }
      else if (j < 60) { py = 29;     px = j - 30; }
      else if (j < 88) { py = j - 59; px = 0;      }
      else             { py = j - 87; px = 29;     }
      roiP[(((size_t)(r * 2 + (c >> 5)) * PP) + py * PW + px) * 32 + (c & 31)] = f2b(0.f);
    }
    return;
  }
  const int wave = t >> 6, c = t & 63;
  const int bi = r >> 5;
  const int ind = act_ind[r];
  const float cx = (float)(ind % HWF), cy = (float)(ind / HWF);
  const float hw = awh[r * 2 + 0] * 0.5f, hh = awh[r * 2 + 1] * 0.5f;
  const float x1b = cx - hw, y1b = cy - hh;
  const float bw = hw / 14.f, bh = hh / 14.f;
  const bf16* fb = featT + (size_t)bi * HWF * HWF * 64;
  for (int pp = part * 112 + wave; pp < part * 112 + 112; pp += 4) {
    int ry = pp / 28, rx = pp % 28;
    float acc = 0.f;
#pragma unroll
    for (int a = 0; a < 2; ++a) {
      int syi = 2 * ry + a;
      float ys = y1b + ((float)syi * 0.5f + 0.25f) * bh;
      ys = fminf(fmaxf(ys, 0.f), 127.f);
      int y0 = (int)floorf(ys); int y1i = min(y0 + 1, 127);
      float wy = ys - (float)y0;
#pragma unroll
      for (int b2 = 0; b2 < 2; ++b2) {
        int sxi = 2 * rx + b2;
        float xs = x1b + ((float)sxi * 0.5f + 0.25f) * bw;
        xs = fminf(fmaxf(xs, 0.f), 127.f);
        int x0 = (int)floorf(xs); int x1i = min(x0 + 1, 127);
        float wx = xs - (float)x0;
        float v00 = b2f(fb[((size_t)y0  * HWF + x0 ) * 64 + c]);
        float v01 = b2f(fb[((size_t)y0  * HWF + x1i) * 64 + c]);
        float v10 = b2f(fb[((size_t)y1i * HWF + x0 ) * 64 + c]);
        float v11 = b2f(fb[((size_t)y1i * HWF + x1i) * 64 + c]);
        float r0 = v00 * (1.f - wy) + v10 * wy;
        float r1 = v01 * (1.f - wy) + v11 * wy;
        acc += r0 * (1.f - wx) + r1 * wx;
      }
    }
    int slot = (ry + 1) * PW + (rx + 1);
    roiP[(((size_t)(r * 2 + (c >> 5)) * PP) + slot) * 32 + (c & 31)] = f2b(acc * 0.25f);
  }
}

// ---------------------------------------------------------------------------
// 32x32x16-MFMA implicit-GEMM conv3x3 + bias + ReLU, mg-split blocks.
// R21: 128-thread blocks (2 waves), wave tile 2mf x 4nf (reads/MFMA 0.75,
// in-wave ILP 8) + R19 LDS diet (54.2KB: A 2x18432 kh-ring + B single 17408)
// -> 3 blocks/CU = 6 waves/CU = 1.5 waves/SIMD. Schedule identical to R19.
// ---------------------------------------------------------------------------
template <int CIN>
__global__ __launch_bounds__(128, 2) void conv_mfma(const bf16* __restrict__ X,
                                                    const bf16* __restrict__ Wt,
                                                    const float* __restrict__ bias,
                                                    bf16* __restrict__ Y) {
  constexpr int NCIB = CIN / 32;
  const int d = blockIdx.x;
  const int xcd = d & 7, sub = d >> 3;          // 128 blocks per XCD
  const int img = xcd * 8 + (sub >> 4);         // 8 imgs per XCD
  const int sm  = sub & 15;
  const int sb  = sm >> 2;                      // strip 0..3 (210 slots)
  const int mg  = sm & 3;                       // co-group (64 co)
  const int s0  = 30 + sb * 210;
  const int gbase = s0 - 31;
  const int t = threadIdx.x;
  const int wave = t >> 6, lane = t & 63;
  const int hi = lane >> 5, l31 = lane & 31;
  const int ng = wave;                          // 2 ng groups

  __shared__ char lds_raw[54272];               // A: 2 x 18432 ; B: 1 x 17408
  char* Ab = lds_raw;
  char* Bb = lds_raw + 36864;

  // ---- B staging precompute: 1088 chunks of 16B, 9 rounds of 128 ----
  int bsrc[9]; bool bok[9];
#pragma unroll
  for (int r = 0; r < 9; ++r) {
    int chunk = r * 128 + t;
    bok[r] = (chunk < 1088);
    int ss = chunk >> 2, up = chunk & 3;
    int u = up ^ ((ss >> 2) & 3);
    int q = gbase + ss; q = q < 0 ? 0 : (q > 899 ? 899 : q);
    bsrc[r] = q * 64 + u * 16;
  }

#define STAGE_B(CIB)                                                             \
  {                                                                              \
    const char* Xc = (const char*)X + ((size_t)(img * NCIB + (CIB)) * 900) * 64; \
    _Pragma("unroll")                                                            \
    for (int r = 0; r < 9; ++r) {                                                \
      if (bok[r]) {                                                              \
        __builtin_amdgcn_global_load_lds(                                        \
            (const __attribute__((address_space(1))) unsigned int*)(Xc + bsrc[r]),\
            (__attribute__((address_space(3))) unsigned int*)                    \
                (Bb + (r * 128 + t) * 16), 16, 0, 0);                            \
      }                                                                          \
    }                                                                            \
  }

  // ---- A staging: per (cib,kh), 1152 chunks of 16B, exactly 9 rounds ----
  int asr[9];
#pragma unroll
  for (int r = 0; r < 9; ++r) {
    int chunk = r * 128 + t;
    int tap = chunk >> 7, within = chunk & 127;
    int s = within ^ ((within >> 3) & 7);
    asr[r] = tap * (NCIB * 2 * 8192) + mg * 2048 + s * 16;
  }

#define STAGE_A(CIB, KH, ABSEL)                                                  \
  {                                                                              \
    const char* Wb = (const char*)Wt + ((CIB) * 2 + (KH)) * 8192;                \
    _Pragma("unroll")                                                            \
    for (int r = 0; r < 9; ++r) {                                                \
      __builtin_amdgcn_global_load_lds(                                          \
          (const __attribute__((address_space(1))) unsigned int*)(Wb + asr[r]),  \
          (__attribute__((address_space(3))) unsigned int*)                      \
              (Ab + (ABSEL) * 18432 + (r * 128 + t) * 16), 16, 0, 0);            \
    }                                                                            \
  }

  f32x16 acc[2][4];
#pragma unroll
  for (int mf = 0; mf < 2; ++mf)
#pragma unroll
    for (int nf = 0; nf < 4; ++nf)
#pragma unroll
      for (int e = 0; e < 16; ++e) acc[mf][nf][e] = 0.f;

  int soc[4];
#pragma unroll
  for (int nf = 0; nf < 4; ++nf) {
    int so = ng * 105 + nf * 32 + l31;
    soc[nf] = (so > 209 ? 209 : so) + 31;
  }
  // A-read lane offset within a (tap,kh) 2KB block (mf adds 1024)
  const int gl0 = 2 * l31 + hi;
  const int apos = (gl0 ^ ((gl0 >> 3) & 7)) * 16;

  constexpr int DTP9[9] = { -31, -30, -29, -1, 0, 1, 29, 30, 31 };

#define LOADA(A, AB, T)                                                          \
  {                                                                              \
    _Pragma("unroll")                                                            \
    for (int mf = 0; mf < 2; ++mf)                                               \
      A[mf] = *(const short8*)((AB) + (T) * 2048 + mf * 1024 + apos);            \
  }

#define LOADB(B, LB, T, KH)                                                      \
  {                                                                              \
    _Pragma("unroll")                                                            \
    for (int nf = 0; nf < 4; ++nf) {                                             \
      int ss = soc[nf] + DTP9[(T)];                                              \
      int u = (((KH) << 1) + hi) ^ ((ss >> 2) & 3);                              \
      B[nf] = *(const short8*)((LB) + ss * 64 + (u << 4));                       \
    }                                                                            \
  }

#define DOMFMA(A, B)                                                             \
  {                                                                              \
    _Pragma("unroll")                                                            \
    for (int mf = 0; mf < 2; ++mf)                                               \
      _Pragma("unroll")                                                          \
      for (int nf = 0; nf < 4; ++nf)                                             \
        acc[mf][nf] = __builtin_amdgcn_mfma_f32_32x32x16_bf16(                   \
            A[mf], B[nf], acc[mf][nf], 0, 0, 0);                                 \
  }

#define JLOOP(KH, AB, LB)                                                        \
  {                                                                              \
    short8 a0[2], b0[4], a1[2], b1[4];                                           \
    LOADA(a0, AB, 0); LOADB(b0, LB, 0, KH);                                      \
    LOADA(a1, AB, 1); LOADB(b1, LB, 1, KH);                                      \
    DOMFMA(a0, b0);                                                              \
    LOADA(a0, AB, 2); LOADB(b0, LB, 2, KH);                                      \
    DOMFMA(a1, b1);                                                              \
    LOADA(a1, AB, 3); LOADB(b1, LB, 3, KH);                                      \
    DOMFMA(a0, b0);                                                              \
    LOADA(a0, AB, 4); LOADB(b0, LB, 4, KH);                                      \
    DOMFMA(a1, b1);                                                              \
    LOADA(a1, AB, 5); LOADB(b1, LB, 5, KH);                                      \
    DOMFMA(a0, b0);                                                              \
    LOADA(a0, AB, 6); LOADB(b0, LB, 6, KH);                                      \
    DOMFMA(a1, b1);                                                              \
    LOADA(a1, AB, 7); LOADB(b1, LB, 7, KH);                                      \
    DOMFMA(a0, b0);                                                              \
    LOADA(a0, AB, 8); LOADB(b0, LB, 8, KH);                                      \
    DOMFMA(a1, b1);                                                              \
    DOMFMA(a0, b0);                                                              \
  }

  // prologue: A(0) both halves, B(0)
  STAGE_A(0, 0, 0);
  STAGE_A(0, 1, 1);
  STAGE_B(0);
  __syncthreads();

  for (int cib = 0; cib < NCIB; ++cib) {
    JLOOP(0, Ab, Bb);
    JLOOP(1, Ab + 18432, Bb);
    __syncthreads();                    // all waves done reading A & B
    if (cib + 1 < NCIB) {
      STAGE_A(cib + 1, 0, 0);
      STAGE_A(cib + 1, 1, 1);
      STAGE_B(cib + 1);
      __syncthreads();                  // DMA complete (barrier drains vmcnt)
    }
  }

  // ---------------- epilogue: LDS bounce -> full 64B-line stores ------------
  {
    f32x4 bv[2][4];
#pragma unroll
    for (int mf = 0; mf < 2; ++mf)
#pragma unroll
      for (int rq = 0; rq < 4; ++rq)
        bv[mf][rq] = *(const f32x4*)(bias + mg * 64 + mf * 32 + 8 * rq + 4 * hi);
#pragma unroll
    for (int mf = 0; mf < 2; ++mf) {
#pragma unroll
      for (int nf = 0; nf < 4; ++nf) {
        int so = ng * 105 + nf * 32 + l31;
        if (so < 210) {
#pragma unroll
          for (int rq = 0; rq < 4; ++rq) {
            float r0 = fmaxf(acc[mf][nf][4*rq+0] + bv[mf][rq][0], 0.f);
            float r1 = fmaxf(acc[mf][nf][4*rq+1] + bv[mf][rq][1], 0.f);
            float r2 = fmaxf(acc[mf][nf][4*rq+2] + bv[mf][rq][2], 0.f);
            float r3 = fmaxf(acc[mf][nf][4*rq+3] + bv[mf][rq][3], 0.f);
            u32x2 pk; pk.x = pack2(r0, r1); pk.y = pack2(r2, r3);
            int cb = mf * 64 + rq * 16 + hi * 8;
            *(u32x2*)(lds_raw + so * 128 + ((cb + so * 8) & 127)) = pk;
          }
        }
      }
    }
  }
  __syncthreads();

  {
    // 210 slots x 2 cob x 4 q16 = 1680 units of 16B; 14 rounds of 128
#pragma unroll
    for (int p = 0; p < 14; ++p) {
      int idx = p * 128 + t;
      if (idx < 1680) {
        int slot = idx >> 3, rem = idx & 7;
        int cob_l = rem >> 2, q = rem & 3;
        int gslot = s0 + slot;
        int c = gslot % 30;
        u32x4 o;
        if (c == 0 || c == 29) { o.x = 0u; o.y = 0u; o.z = 0u; o.w = 0u; }
        else {
          int cb0 = cob_l * 64 + q * 16;
          u32x2 v0 = *(u32x2*)(lds_raw + slot * 128 + ((cb0 + 0 + slot * 8) & 127));
          u32x2 v1 = *(u32x2*)(lds_raw + slot * 128 + ((cb0 + 8 + slot * 8) & 127));
          o.x = v0.x; o.y = v0.y; o.z = v1.x; o.w = v1.y;
        }
        *(u32x4*)((char*)Y + ((size_t)(img * 8 + mg * 2 + cob_l) * 900 + gslot) * 64
                  + q * 16) = o;
      }
    }
  }
  // row 0 / row 29 zeroing (sb 0 and 3), this block's 2 cobs only
  if (sb == 0 || sb == 3) {
    const int rowslot = (sb == 0) ? 0 : 870;
    for (int i = t; i < 240; i += 128) {
      int slot_z = i >> 3, rem = i & 7;
      int cob_l = rem >> 2, q = rem & 3;
      u32x4 z; z.x = 0u; z.y = 0u; z.z = 0u; z.w = 0u;
      *(u32x4*)((char*)Y + ((size_t)(img * 8 + mg * 2 + cob_l) * 900
                + rowslot + slot_z) * 64 + q * 16) = z;
    }
  }
}

// ---------------------------------------------------------------------------
// Head: one pixel per thread. grid 196 x 256 = 50176 = 64 img x 784 px.
// ---------------------------------------------------------------------------
__global__ __launch_bounds__(256) void head_cl(const bf16* __restrict__ X,
                                               const float* __restrict__ Weff,
                                               const float* __restrict__ beff,
                                               float* __restrict__ out) {
  const int idx = blockIdx.x * 256 + threadIdx.x;
  const int img = idx / 784, p = idx % 784;
  const float bo0 = beff[0], bo1 = beff[1], bo2 = beff[2];
  int iy = p / 28, ix = p % 28;
  int slot = (iy + 1) * PW + ix + 1;
  float acc[12];
#pragma unroll
  for (int k = 0; k < 12; ++k) acc[k] = 0.f;
  for (int cob = 0; cob < 8; ++cob) {
    const bf16* xp = X + ((size_t)(img * 8 + cob) * PP + slot) * 32;
#pragma unroll
    for (int oct = 0; oct < 4; ++oct) {
      short8 v = *(const short8*)(xp + oct * 8);
#pragma unroll
      for (int j = 0; j < 8; ++j) {
        float xv = u2f((unsigned short)v[j]);
        int ci = cob * 32 + oct * 8 + j;
#pragma unroll
        for (int k = 0; k < 12; ++k)
          acc[k] += xv * Weff[k * 256 + ci];
      }
    }
  }
#pragma unroll
  for (int k4 = 0; k4 < 4; ++k4) {
    int oy = 2 * iy + (k4 >> 1), ox = 2 * ix + (k4 & 1);
    out[(((size_t)(img * 3 + 0)) * 56 + oy) * 56 + ox] = acc[k4 * 3 + 0] + bo0;
    out[(((size_t)(img * 3 + 1)) * 56 + oy) * 56 + ox] = acc[k4 * 3 + 1] + bo1;
    out[(((size_t)(img * 3 + 2)) * 56 + oy) * 56 + ox] = acc[k4 * 3 + 2] + bo2;
  }
}

// ---------------------------------------------------------------------------
extern "C" void kernel_launch(void* const* d_in, const int* in_sizes, int n_in,
                              void* d_out, int out_size, void* d_ws, size_t ws_size,
                              hipStream_t stream) {
  const float* feat    = (const float*)d_in[0];
  const int*   act_ind = (const int*)  d_in[1];
  const float* awh     = (const float*)d_in[2];
  const float* w1 = (const float*)d_in[3];  const float* b1 = (const float*)d_in[4];
  const float* w2 = (const float*)d_in[5];  const float* b2 = (const float*)d_in[6];
  const float* w3 = (const float*)d_in[7];  const float* b3 = (const float*)d_in[8];
  const float* w4 = (const float*)d_in[9];  const float* b4 = (const float*)d_in[10];
  const float* hm_dw = (const float*)d_in[11]; const float* hm_db = (const float*)d_in[12];
  const float* hm_w  = (const float*)d_in[13]; const float* hm_b  = (const float*)d_in[14];
  const float* wh_dw = (const float*)d_in[15]; const float* wh_db = (const float*)d_in[16];
  const float* wh_w  = (const float*)d_in[17]; const float* wh_b  = (const float*)d_in[18];

  char* ws = (char*)d_ws;
  size_t offset = 0;
  auto alloc = [&](size_t bytes) {
    size_t r = offset;
    offset += (bytes + 255) & ~(size_t)255;
    return r;
  };
  float* Weff = (float*)(ws + alloc(12 * 256 * sizeof(float)));
  float* beff = (float*)(ws + alloc(256));
  bf16*  Wt1  = (bf16*)(ws + alloc((size_t)9 * 256 * 64  * 2));
  bf16*  Wt2  = (bf16*)(ws + alloc((size_t)9 * 256 * 256 * 2));
  bf16*  Wt3  = (bf16*)(ws + alloc((size_t)9 * 256 * 256 * 2));
  bf16*  Wt4  = (bf16*)(ws + alloc((size_t)9 * 256 * 256 * 2));
  bf16*  bufA = (bf16*)(ws + alloc((size_t)NB * 256 * PP * 2));
  bf16*  bufB = (bf16*)(ws + alloc((size_t)NB * 256 * PP * 2));
  // aliases inside bufB (dead before conv2 writes bufB):
  bf16*  roiP  = bufB;                                   // 7.37 MB
  bf16*  featT = (bf16*)((char*)bufB + (8u << 20));      // 4.19 MB at +8MB

  prep_kernel<<<1036, 256, 0, stream>>>(hm_dw, hm_db, hm_w, hm_b,
                                        wh_dw, wh_db, wh_w, wh_b, Weff, beff,
                                        w1, Wt1, w2, Wt2, w3, Wt3, w4, Wt4);
  featT_kernel<<<256, 256, 0, stream>>>(feat, featT);
  roi_cl<<<dim3(NB, 8), 256, 0, stream>>>(featT, act_ind, awh, roiP);
  conv_mfma<64> <<<1024, 128, 0, stream>>>(roiP, Wt1, b1, bufA);
  conv_mfma<256><<<1024, 128, 0, stream>>>(bufA, Wt2, b2, bufB);
  conv_mfma<256><<<1024, 128, 0, stream>>>(bufB, Wt3, b3, bufA);
  conv_mfma<256><<<1024, 128, 0, stream>>>(bufA, Wt4, b4, bufB);
  head_cl<<<196, 256, 0, stream>>>(bufB, Weff, beff, (float*)d_out);
}

// Round 22
// 331.262 us; speedup vs baseline: 1.3505x; 1.3505x over previous
//
#include <hip/hip_runtime.h>
#include <hip/hip_bf16.h>

#define HWF 128
#define NB  64
#define PW  30
#define PP  900

using bf16 = __hip_bfloat16;
typedef __attribute__((ext_vector_type(8)))  short short8;
typedef __attribute__((ext_vector_type(4)))  float f32x4;
typedef __attribute__((ext_vector_type(16))) float f32x16;
typedef __attribute__((ext_vector_type(4)))  unsigned int u32x4;
typedef __attribute__((ext_vector_type(2)))  unsigned int u32x2;

__device__ __forceinline__ float b2f(bf16 v) { return __bfloat162float(v); }
__device__ __forceinline__ bf16  f2b(float v){ return __float2bfloat16(v); }
__device__ __forceinline__ float u2f(unsigned short u){ unsigned x = (unsigned)u << 16; float f; __builtin_memcpy(&f,&x,4); return f; }
__device__ __forceinline__ unsigned pack2(float a, float b) {
  union { bf16 h; unsigned short u; } ca, cb; ca.h = f2b(a); cb.h = f2b(b);
  return ((unsigned)cb.u << 16) | (unsigned)ca.u;
}

// ---------------------------------------------------------------------------
// Fused prep: blocks 0..11 = head fold (weff); blocks 12..1035 = weight
// transforms w[co][ci][3][3] fp32 -> Wt[tap][cib][kh][co][koct][8e] bf16.
// ---------------------------------------------------------------------------
__global__ __launch_bounds__(256) void prep_kernel(
    const float* __restrict__ hm_dw, const float* __restrict__ hm_db,
    const float* __restrict__ hm_w,  const float* __restrict__ hm_b,
    const float* __restrict__ wh_dw, const float* __restrict__ wh_db,
    const float* __restrict__ wh_w,  const float* __restrict__ wh_b,
    float* __restrict__ Weff, float* __restrict__ beff,
    const float* __restrict__ w1, bf16* __restrict__ Wt1,
    const float* __restrict__ w2, bf16* __restrict__ Wt2,
    const float* __restrict__ w3, bf16* __restrict__ Wt3,
    const float* __restrict__ w4, bf16* __restrict__ Wt4) {
  const int b = blockIdx.x;
  if (b < 12) {
    const int k = b / 3, o = b % 3;
    const int ci = threadIdx.x;
    const float* dw = (o == 0) ? hm_dw : wh_dw;
    const float* hw = (o == 0) ? hm_w  : (wh_w + (size_t)(o - 1) * 256);
    const float* dwp = dw + (size_t)ci * 4 + k;
    float s = 0.f;
    for (int co = 0; co < 256; ++co) s += hw[co] * dwp[(size_t)co * 1024];
    Weff[(size_t)b * 256 + ci] = s;
    if (k == 0 && ci == 0) {
      const float* db = (o == 0) ? hm_db : wh_db;
      float bb = (o == 0) ? hm_b[0] : wh_b[o - 1];
      float t = 0.f;
      for (int co = 0; co < 256; ++co) t += hw[co] * db[co];
      beff[o] = bb + t;
    }
    return;
  }
  const int i = b - 12;
  const int layer = i >> 8, co = i & 255;
  const float* w; bf16* Wt; int CIN;
  if      (layer == 0) { w = w1; Wt = Wt1; CIN = 64;  }
  else if (layer == 1) { w = w2; Wt = Wt2; CIN = 256; }
  else if (layer == 2) { w = w3; Wt = Wt3; CIN = 256; }
  else                 { w = w4; Wt = Wt4; CIN = 256; }
  const int ci = threadIdx.x;
  if (ci < CIN) {
    const int NCIB = CIN >> 5;
    const int cib = ci >> 5, cl = ci & 31;
    const int kh = cl >> 4, koct = (cl >> 3) & 1, e = ci & 7;
    for (int tap = 0; tap < 9; ++tap)
      Wt[(((((size_t)tap * NCIB + cib) * 2 + kh) * 256 + co) * 2 + koct) * 8 + e]
          = f2b(w[((size_t)co * CIN + ci) * 9 + tap]);
  }
}

// ---------------------------------------------------------------------------
// Feature transpose (unchanged, verified)
// ---------------------------------------------------------------------------
__global__ __launch_bounds__(256) void featT_kernel(const float* __restrict__ feat,
                                                    bf16* __restrict__ featT) {
  const int by = blockIdx.x;
  const int b = by >> 7, y = by & 127;
  const int t = threadIdx.x;
  __shared__ float tile[128][65];
  const int xr = t & 127, c2 = t >> 7;
  for (int c0 = 0; c0 < 64; c0 += 2)
    tile[xr][c0 + c2] = feat[(((size_t)(b * 64 + c0 + c2) * 128 + y) * 128) + xr];
  __syncthreads();
  const int cw = t & 63, x4 = t >> 6;
  for (int x0 = 0; x0 < 128; x0 += 4)
    featT[(((size_t)by * 128) + x0 + x4) * 64 + cw] = f2b(tile[x0 + x4][cw]);
}

// ---------------------------------------------------------------------------
// ROI align -> roiP cob-blocked: [roi][cb 0..1][900][32ci] bf16, borders zeroed
// ---------------------------------------------------------------------------
__global__ __launch_bounds__(256) void roi_cl(const bf16* __restrict__ featT,
                                              const int* __restrict__ act_ind,
                                              const float* __restrict__ awh,
                                              bf16* __restrict__ roiP) {
  const int r = blockIdx.x, part = blockIdx.y;
  const int t = threadIdx.x;
  if (part == 7) {
    for (int i = t; i < 116 * 64; i += 256) {
      int j = i >> 6, c = i & 63;
      int py, px;
      if (j < 30)      { py = 0;      px = j;      }
      else if (j < 60) { py = 29;     px = j - 30; }
      else if (j < 88) { py = j - 59; px = 0;      }
      else             { py = j - 87; px = 29;     }
      roiP[(((size_t)(r * 2 + (c >> 5)) * PP) + py * PW + px) * 32 + (c & 31)] = f2b(0.f);
    }
    return;
  }
  const int wave = t >> 6, c = t & 63;
  const int bi = r >> 5;
  const int ind = act_ind[r];
  const float cx = (float)(ind % HWF), cy = (float)(ind / HWF);
  const float hw = awh[r * 2 + 0] * 0.5f, hh = awh[r * 2 + 1] * 0.5f;
  const float x1b = cx - hw, y1b = cy - hh;
  const float bw = hw / 14.f, bh = hh / 14.f;
  const bf16* fb = featT + (size_t)bi * HWF * HWF * 64;
  for (int pp = part * 112 + wave; pp < part * 112 + 112; pp += 4) {
    int ry = pp / 28, rx = pp % 28;
    float acc = 0.f;
#pragma unroll
    for (int a = 0; a < 2; ++a) {
      int syi = 2 * ry + a;
      float ys = y1b + ((float)syi * 0.5f + 0.25f) * bh;
      ys = fminf(fmaxf(ys, 0.f), 127.f);
      int y0 = (int)floorf(ys); int y1i = min(y0 + 1, 127);
      float wy = ys - (float)y0;
#pragma unroll
      for (int b2 = 0; b2 < 2; ++b2) {
        int sxi = 2 * rx + b2;
        float xs = x1b + ((float)sxi * 0.5f + 0.25f) * bw;
        xs = fminf(fmaxf(xs, 0.f), 127.f);
        int x0 = (int)floorf(xs); int x1i = min(x0 + 1, 127);
        float wx = xs - (float)x0;
        float v00 = b2f(fb[((size_t)y0  * HWF + x0 ) * 64 + c]);
        float v01 = b2f(fb[((size_t)y0  * HWF + x1i) * 64 + c]);
        float v10 = b2f(fb[((size_t)y1i * HWF + x0 ) * 64 + c]);
        float v11 = b2f(fb[((size_t)y1i * HWF + x1i) * 64 + c]);
        float r0 = v00 * (1.f - wy) + v10 * wy;
        float r1 = v01 * (1.f - wy) + v11 * wy;
        acc += r0 * (1.f - wx) + r1 * wx;
      }
    }
    int slot = (ry + 1) * PW + (rx + 1);
    roiP[(((size_t)(r * 2 + (c >> 5)) * PP) + slot) * 32 + (c & 31)] = f2b(acc * 0.25f);
  }
}

// ---------------------------------------------------------------------------
// 32x32x16-MFMA implicit-GEMM conv3x3 + bias + ReLU, mg-split blocks.
// (R19/R20 champion structure — 256 threads, 2mf x 2nf, LDS 54.2KB)
// ---------------------------------------------------------------------------
template <int CIN>
__global__ __launch_bounds__(256, 3) void conv_mfma(const bf16* __restrict__ X,
                                                    const bf16* __restrict__ Wt,
                                                    const float* __restrict__ bias,
                                                    bf16* __restrict__ Y) {
  constexpr int NCIB = CIN / 32;
  const int d = blockIdx.x;
  const int xcd = d & 7, sub = d >> 3;          // 128 blocks per XCD
  const int img = xcd * 8 + (sub >> 4);         // 8 imgs per XCD
  const int sm  = sub & 15;
  const int sb  = sm >> 2;                      // strip 0..3 (210 slots)
  const int mg  = sm & 3;                       // co-group (64 co)
  const int s0  = 30 + sb * 210;
  const int gbase = s0 - 31;
  const int t = threadIdx.x;
  const int wave = t >> 6, lane = t & 63;
  const int hi = lane >> 5, l31 = lane & 31;
  const int ng = wave;                          // 4 ng groups x 64 slots

  __shared__ char lds_raw[54272];               // A: 2 x 18432 ; B: 1 x 17408
  char* Ab = lds_raw;
  char* Bb = lds_raw + 36864;

  // ---- B staging precompute: 272 slots = 1088 chunks of 16B, 5 rounds ----
  int bsrc[5]; bool bok[5];
#pragma unroll
  for (int r = 0; r < 5; ++r) {
    int chunk = r * 256 + t;
    bok[r] = (chunk < 1088);
    int ss = chunk >> 2, up = chunk & 3;
    int u = up ^ ((ss >> 2) & 3);
    int q = gbase + ss; q = q < 0 ? 0 : (q > 899 ? 899 : q);
    bsrc[r] = q * 64 + u * 16;
  }

#define STAGE_B(CIB)                                                             \
  {                                                                              \
    const char* Xc = (const char*)X + ((size_t)(img * NCIB + (CIB)) * 900) * 64; \
    _Pragma("unroll")                                                            \
    for (int r = 0; r < 5; ++r) {                                                \
      if (bok[r]) {                                                              \
        __builtin_amdgcn_global_load_lds(                                        \
            (const __attribute__((address_space(1))) unsigned int*)(Xc + bsrc[r]),\
            (__attribute__((address_space(3))) unsigned int*)                    \
                (Bb + r * 4096 + wave * 1024), 16, 0, 0);                        \
      }                                                                          \
    }                                                                            \
  }

  // ---- A staging: per (cib,kh), 18432B = 1152 chunks of 16B, 5 rounds ----
  int asr[5]; bool aok[5];
#pragma unroll
  for (int r = 0; r < 5; ++r) {
    int chunk = r * 256 + t;
    aok[r] = (chunk < 1152);
    int tap = chunk >> 7, within = chunk & 127;
    int s = within ^ ((within >> 3) & 7);
    asr[r] = tap * (NCIB * 2 * 8192) + mg * 2048 + s * 16;
  }

#define STAGE_A(CIB, KH, ABSEL)                                                  \
  {                                                                              \
    const char* Wb = (const char*)Wt + ((CIB) * 2 + (KH)) * 8192;                \
    _Pragma("unroll")                                                            \
    for (int r = 0; r < 5; ++r) {                                                \
      if (aok[r]) {                                                              \
        __builtin_amdgcn_global_load_lds(                                        \
            (const __attribute__((address_space(1))) unsigned int*)(Wb + asr[r]),\
            (__attribute__((address_space(3))) unsigned int*)                    \
                (Ab + (ABSEL) * 18432 + (r * 256 + wave * 64) * 16), 16, 0, 0);  \
      }                                                                          \
    }                                                                            \
  }

  f32x16 acc[2][2];
#pragma unroll
  for (int mf = 0; mf < 2; ++mf)
#pragma unroll
    for (int nf = 0; nf < 2; ++nf)
#pragma unroll
      for (int e = 0; e < 16; ++e) acc[mf][nf][e] = 0.f;

  int soc[2];
#pragma unroll
  for (int nf = 0; nf < 2; ++nf) {
    int so = ng * 64 + nf * 32 + l31;
    soc[nf] = (so > 209 ? 209 : so) + 31;
  }
  // A-read lane offset within a (tap,kh) 2KB block (mf adds 1024)
  const int gl0 = 2 * l31 + hi;
  const int apos = (gl0 ^ ((gl0 >> 3) & 7)) * 16;

  constexpr int DTP9[9] = { -31, -30, -29, -1, 0, 1, 29, 30, 31 };

#define LOADA(A, AB, T)                                                          \
  {                                                                              \
    _Pragma("unroll")                                                            \
    for (int mf = 0; mf < 2; ++mf)                                               \
      A[mf] = *(const short8*)((AB) + (T) * 2048 + mf * 1024 + apos);            \
  }

#define LOADB(B, LB, T, KH)                                                      \
  {                                                                              \
    _Pragma("unroll")                                                            \
    for (int nf = 0; nf < 2; ++nf) {                                             \
      int ss = soc[nf] + DTP9[(T)];                                              \
      int u = (((KH) << 1) + hi) ^ ((ss >> 2) & 3);                              \
      B[nf] = *(const short8*)((LB) + ss * 64 + (u << 4));                       \
    }                                                                            \
  }

#define DOMFMA(A, B)                                                             \
  {                                                                              \
    _Pragma("unroll")                                                            \
    for (int mf = 0; mf < 2; ++mf)                                               \
      _Pragma("unroll")                                                          \
      for (int nf = 0; nf < 2; ++nf)                                             \
        acc[mf][nf] = __builtin_amdgcn_mfma_f32_32x32x16_bf16(                   \
            A[mf], B[nf], acc[mf][nf], 0, 0, 0);                                 \
  }

#define JLOOP(KH, AB, LB)                                                        \
  {                                                                              \
    short8 a0[2], b0[2], a1[2], b1[2];                                           \
    LOADA(a0, AB, 0); LOADB(b0, LB, 0, KH);                                      \
    LOADA(a1, AB, 1); LOADB(b1, LB, 1, KH);                                      \
    DOMFMA(a0, b0);                                                              \
    LOADA(a0, AB, 2); LOADB(b0, LB, 2, KH);                                      \
    DOMFMA(a1, b1);                                                              \
    LOADA(a1, AB, 3); LOADB(b1, LB, 3, KH);                                      \
    DOMFMA(a0, b0);                                                              \
    LOADA(a0, AB, 4); LOADB(b0, LB, 4, KH);                                      \
    DOMFMA(a1, b1);                                                              \
    LOADA(a1, AB, 5); LOADB(b1, LB, 5, KH);                                      \
    DOMFMA(a0, b0);                                                              \
    LOADA(a0, AB, 6); LOADB(b0, LB, 6, KH);                                      \
    DOMFMA(a1, b1);                                                              \
    LOADA(a1, AB, 7); LOADB(b1, LB, 7, KH);                                      \
    DOMFMA(a0, b0);                                                              \
    LOADA(a0, AB, 8); LOADB(b0, LB, 8, KH);                                      \
    DOMFMA(a1, b1);                                                              \
    DOMFMA(a0, b0);                                                              \
  }

  // prologue: A(0) both halves, B(0)
  STAGE_A(0, 0, 0);
  STAGE_A(0, 1, 1);
  STAGE_B(0);
  __syncthreads();

  for (int cib = 0; cib < NCIB; ++cib) {
    JLOOP(0, Ab, Bb);
    JLOOP(1, Ab + 18432, Bb);
    __syncthreads();                    // all waves done reading A & B
    if (cib + 1 < NCIB) {
      STAGE_A(cib + 1, 0, 0);
      STAGE_A(cib + 1, 1, 1);
      STAGE_B(cib + 1);
      __syncthreads();                  // DMA complete (barrier drains vmcnt)
    }
  }

  // ---------------- epilogue: LDS bounce -> full 64B-line stores ------------
  {
    f32x4 bv[2][4];
#pragma unroll
    for (int mf = 0; mf < 2; ++mf)
#pragma unroll
      for (int rq = 0; rq < 4; ++rq)
        bv[mf][rq] = *(const f32x4*)(bias + mg * 64 + mf * 32 + 8 * rq + 4 * hi);
#pragma unroll
    for (int mf = 0; mf < 2; ++mf) {
#pragma unroll
      for (int nf = 0; nf < 2; ++nf) {
        int so = ng * 64 + nf * 32 + l31;
        if (so < 210) {
#pragma unroll
          for (int rq = 0; rq < 4; ++rq) {
            float r0 = fmaxf(acc[mf][nf][4*rq+0] + bv[mf][rq][0], 0.f);
            float r1 = fmaxf(acc[mf][nf][4*rq+1] + bv[mf][rq][1], 0.f);
            float r2 = fmaxf(acc[mf][nf][4*rq+2] + bv[mf][rq][2], 0.f);
            float r3 = fmaxf(acc[mf][nf][4*rq+3] + bv[mf][rq][3], 0.f);
            u32x2 pk; pk.x = pack2(r0, r1); pk.y = pack2(r2, r3);
            int cb = mf * 64 + rq * 16 + hi * 8;
            *(u32x2*)(lds_raw + so * 128 + ((cb + so * 8) & 127)) = pk;
          }
        }
      }
    }
  }
  __syncthreads();

  {
    // 210 slots x 2 cob x 4 q16 = 1680 units of 16B; 7 rounds of 256
#pragma unroll
    for (int p = 0; p < 7; ++p) {
      int idx = p * 256 + t;
      if (idx < 1680) {
        int slot = idx >> 3, rem = idx & 7;
        int cob_l = rem >> 2, q = rem & 3;
        int gslot = s0 + slot;
        int c = gslot % 30;
        u32x4 o;
        if (c == 0 || c == 29) { o.x = 0u; o.y = 0u; o.z = 0u; o.w = 0u; }
        else {
          int cb0 = cob_l * 64 + q * 16;
          u32x2 v0 = *(u32x2*)(lds_raw + slot * 128 + ((cb0 + 0 + slot * 8) & 127));
          u32x2 v1 = *(u32x2*)(lds_raw + slot * 128 + ((cb0 + 8 + slot * 8) & 127));
          o.x = v0.x; o.y = v0.y; o.z = v1.x; o.w = v1.y;
        }
        *(u32x4*)((char*)Y + ((size_t)(img * 8 + mg * 2 + cob_l) * 900 + gslot) * 64
                  + q * 16) = o;
      }
    }
  }
  // row 0 / row 29 zeroing (sb 0 and 3), this block's 2 cobs only
  if (sb == 0 || sb == 3) {
    const int rowslot = (sb == 0) ? 0 : 870;
    if (t < 240) {
      int slot_z = t >> 3, rem = t & 7;
      int cob_l = rem >> 2, q = rem & 3;
      if (q < 4 && cob_l < 2) {
        u32x4 z; z.x = 0u; z.y = 0u; z.z = 0u; z.w = 0u;
        *(u32x4*)((char*)Y + ((size_t)(img * 8 + mg * 2 + cob_l) * 900
                  + rowslot + slot_z) * 64 + q * 16) = z;
      }
    }
  }
}

// ---------------------------------------------------------------------------
// Head: one pixel per thread. grid 196 x 256 = 50176 = 64 img x 784 px.
// ---------------------------------------------------------------------------
__global__ __launch_bounds__(256) void head_cl(const bf16* __restrict__ X,
                                               const float* __restrict__ Weff,
                                               const float* __restrict__ beff,
                                               float* __restrict__ out) {
  const int idx = blockIdx.x * 256 + threadIdx.x;
  const int img = idx / 784, p = idx % 784;
  const float bo0 = beff[0], bo1 = beff[1], bo2 = beff[2];
  int iy = p / 28, ix = p % 28;
  int slot = (iy + 1) * PW + ix + 1;
  float acc[12];
#pragma unroll
  for (int k = 0; k < 12; ++k) acc[k] = 0.f;
  for (int cob = 0; cob < 8; ++cob) {
    const bf16* xp = X + ((size_t)(img * 8 + cob) * PP + slot) * 32;
#pragma unroll
    for (int oct = 0; oct < 4; ++oct) {
      short8 v = *(const short8*)(xp + oct * 8);
#pragma unroll
      for (int j = 0; j < 8; ++j) {
        float xv = u2f((unsigned short)v[j]);
        int ci = cob * 32 + oct * 8 + j;
#pragma unroll
        for (int k = 0; k < 12; ++k)
          acc[k] += xv * Weff[k * 256 + ci];
      }
    }
  }
#pragma unroll
  for (int k4 = 0; k4 < 4; ++k4) {
    int oy = 2 * iy + (k4 >> 1), ox = 2 * ix + (k4 & 1);
    out[(((size_t)(img * 3 + 0)) * 56 + oy) * 56 + ox] = acc[k4 * 3 + 0] + bo0;
    out[(((size_t)(img * 3 + 1)) * 56 + oy) * 56 + ox] = acc[k4 * 3 + 1] + bo1;
    out[(((size_t)(img * 3 + 2)) * 56 + oy) * 56 + ox] = acc[k4 * 3 + 2] + bo2;
  }
}

// ---------------------------------------------------------------------------
extern "C" void kernel_launch(void* const* d_in, const int* in_sizes, int n_in,
                              void* d_out, int out_size, void* d_ws, size_t ws_size,
                              hipStream_t stream) {
  const float* feat    = (const float*)d_in[0];
  const int*   act_ind = (const int*)  d_in[1];
  const float* awh     = (const float*)d_in[2];
  const float* w1 = (const float*)d_in[3];  const float* b1 = (const float*)d_in[4];
  const float* w2 = (const float*)d_in[5];  const float* b2 = (const float*)d_in[6];
  const float* w3 = (const float*)d_in[7];  const float* b3 = (const float*)d_in[8];
  const float* w4 = (const float*)d_in[9];  const float* b4 = (const float*)d_in[10];
  const float* hm_dw = (const float*)d_in[11]; const float* hm_db = (const float*)d_in[12];
  const float* hm_w  = (const float*)d_in[13]; const float* hm_b  = (const float*)d_in[14];
  const float* wh_dw = (const float*)d_in[15]; const float* wh_db = (const float*)d_in[16];
  const float* wh_w  = (const float*)d_in[17]; const float* wh_b  = (const float*)d_in[18];

  char* ws = (char*)d_ws;
  size_t offset = 0;
  auto alloc = [&](size_t bytes) {
    size_t r = offset;
    offset += (bytes + 255) & ~(size_t)255;
    return r;
  };
  float* Weff = (float*)(ws + alloc(12 * 256 * sizeof(float)));
  float* beff = (float*)(ws + alloc(256));
  bf16*  Wt1  = (bf16*)(ws + alloc((size_t)9 * 256 * 64  * 2));
  bf16*  Wt2  = (bf16*)(ws + alloc((size_t)9 * 256 * 256 * 2));
  bf16*  Wt3  = (bf16*)(ws + alloc((size_t)9 * 256 * 256 * 2));
  bf16*  Wt4  = (bf16*)(ws + alloc((size_t)9 * 256 * 256 * 2));
  bf16*  bufA = (bf16*)(ws + alloc((size_t)NB * 256 * PP * 2));
  bf16*  bufB = (bf16*)(ws + alloc((size_t)NB * 256 * PP * 2));
  // aliases inside bufB (dead before conv2 writes bufB):
  bf16*  roiP  = bufB;                                   // 7.37 MB
  bf16*  featT = (bf16*)((char*)bufB + (8u << 20));      // 4.19 MB at +8MB

  prep_kernel<<<1036, 256, 0, stream>>>(hm_dw, hm_db, hm_w, hm_b,
                                        wh_dw, wh_db, wh_w, wh_b, Weff, beff,
                                        w1, Wt1, w2, Wt2, w3, Wt3, w4, Wt4);
  featT_kernel<<<256, 256, 0, stream>>>(feat, featT);
  roi_cl<<<dim3(NB, 8), 256, 0, stream>>>(featT, act_ind, awh, roiP);
  conv_mfma<64> <<<1024, 256, 0, stream>>>(roiP, Wt1, b1, bufA);
  conv_mfma<256><<<1024, 256, 0, stream>>>(bufA, Wt2, b2, bufB);
  conv_mfma<256><<<1024, 256, 0, stream>>>(bufB, Wt3, b3, bufA);
  conv_mfma<256><<<1024, 256, 0, stream>>>(bufA, Wt4, b4, bufB);
  head_cl<<<196, 256, 0, stream>>>(bufB, Weff, beff, (float*)d_out);
}